// Round 5
// baseline (325.577 us; speedup 1.0000x reference)
//
#include <hip/hip_runtime.h>
#include <math.h>

#define NB 4
#define NH 16
#define NCC 64
#define CSC 64
#define DC 64
#define S 72            // LDS row stride (bf16): 144B rows, 16B-aligned, stride 36 words
#define EPSF 1e-6f
#define SEQB 56320      // per-sequence LDS bytes

typedef __attribute__((ext_vector_type(8))) short bf16x8;   // MFMA A/B frag (4 VGPR)
typedef __attribute__((ext_vector_type(4))) float f32x4;    // MFMA C/D frag
typedef __attribute__((ext_vector_type(4))) short short4v;

static __device__ __forceinline__ short cvt_bf16(float x) { // RNE f32->bf16
    union { float f; unsigned u; } v; v.f = x;
    unsigned r = v.u + 0x7fffu + ((v.u >> 16) & 1u);
    return (short)(r >> 16);
}
static __device__ __forceinline__ float red16(float v) {    // sum over 16-lane group
    v += __shfl_xor(v, 1); v += __shfl_xor(v, 2);
    v += __shfl_xor(v, 4); v += __shfl_xor(v, 8);
    return v;
}

__global__ __launch_bounds__(512, 1) void ttt_kernel(
    const float* __restrict__ xk, const float* __restrict__ xv,
    const float* __restrict__ weight, const float* __restrict__ bias,
    const float* __restrict__ gamma, const float* __restrict__ beta,
    const float* __restrict__ theta, const float* __restrict__ theta_bias,
    const float* __restrict__ alpha, float* __restrict__ out)
{
    extern __shared__ char smem_raw[];

    const int t  = threadIdx.x;
    const int w  = t >> 6;            // wave 0..7
    const int sq = w >> 2;            // sequence half 0/1
    const int ws = w & 3;             // wave within sequence
    const int l  = t & 63;
    const int g  = l >> 4;
    const int la = l & 15;
    const int ts = 64 * ws + l;       // per-seq thread id 0..255
    const int bh = (blockIdx.x << 1) | sq;   // 0..63
    const int h  = bh & (NH - 1);
    const int r0 = 16 * ws + 4 * g;

    char* sb = smem_raw + sq * SEQB;
    auto xs_rm = (short (*)[S])      (sb);            //  9216: xk row-major (A of z, A/B of Gram)
    auto xsT   = (short (*)[DC][S])  (sb + 9216);     // 18432: xk^T, double-buffered (A of dW)
    auto gsT   = (short (*)[S])      (sb + 27648);    //  9216: gs^T (B of dW and of out)
    auto Gr    = (short (*)[S])      (sb + 36864);    //  9216: Gram (A of out)
    auto Wtb   = (short (*)[S])      (sb + 46080);    //  9216: W [e][d] (B of z)
    auto dbp   = (float (*)[DC])     (sb + 55296);    //  1024: db partials

    // per-col constants (cols e_n = 16n+la)
    float gam[4], bet[4], thv[4], bcol[4];
#pragma unroll
    for (int n = 0; n < 4; ++n) {
        gam[n]  = gamma[h*DC + 16*n + la];
        bet[n]  = beta [h*DC + 16*n + la];
        thv[n]  = theta[h*DC + 16*n + la];
        bcol[n] = bias [h*DC + 16*n + la];
    }
    const float tb = theta_bias[h];
    float tok[4];
#pragma unroll
    for (int i = 0; i < 4; ++i)
        tok[i] = fmaxf(1.0f/(float)(r0+i+1) + alpha[r0+i], 0.0f);

    // W state in regs: Wreg[i][n] = W[r0+i][16n+la]  (dW C-frag layout)
    float Wreg[4][4];
    const float* wg = weight + h*DC*DC;
#pragma unroll
    for (int i = 0; i < 4; ++i)
#pragma unroll
        for (int n = 0; n < 4; ++n)
            Wreg[i][n] = wg[(r0+i)*DC + 16*n + la];
#pragma unroll
    for (int n = 0; n < 4; ++n) {
        short4v sv;
#pragma unroll
        for (int i = 0; i < 4; ++i) sv[i] = cvt_bf16(Wreg[i][n]);
        *(short4v*)&Wtb[16*n + la][r0] = sv;
    }

    const size_t bh_off = (size_t)bh * NCC*CSC*DC;
    const float* xkb = xk + bh_off;
    const float* xvb = xv + bh_off;
    float*       ob  = out + bh_off;

    // chunk-0: fp32 row regs + both LDS layouts
    float4 xl[4];
#pragma unroll
    for (int i4 = 0; i4 < 4; ++i4) xl[i4] = ((const float4*)xkb)[ts + 256*i4];
    float xkg[4][4], xvg[4][4];
#pragma unroll
    for (int i = 0; i < 4; ++i)
#pragma unroll
        for (int n = 0; n < 4; ++n) {
            xkg[i][n] = xkb[(r0+i)*DC + 16*n + la];
            xvg[i][n] = xvb[(r0+i)*DC + 16*n + la];
        }
#pragma unroll
    for (int i4 = 0; i4 < 4; ++i4) {
        int f = ts + 256*i4, k = f >> 4, j = f & 15;
        short4v s4;
        s4[0]=cvt_bf16(xl[i4].x); s4[1]=cvt_bf16(xl[i4].y);
        s4[2]=cvt_bf16(xl[i4].z); s4[3]=cvt_bf16(xl[i4].w);
        *(short4v*)&xs_rm[k][4*j] = s4;
    }
#pragma unroll
    for (int n = 0; n < 4; ++n) {     // xsT[0] from xkg regs: b64, conflict-benign
        short4v sv;
#pragma unroll
        for (int i = 0; i < 4; ++i) sv[i] = cvt_bf16(xkg[i][n]);
        *(short4v*)&xsT[0][16*n + la][r0] = sv;
    }
    __syncthreads();

    for (int c = 0; c < NCC; ++c) {
        const int cb = c & 1;
        if (c + 1 < NCC) {            // prefetch next chunk's row-major staging data
            const float* xkn = xkb + (c+1)*CSC*DC;
#pragma unroll
            for (int i4 = 0; i4 < 4; ++i4) xl[i4] = ((const float4*)xkn)[ts + 256*i4];
        }

        // ---- P1: Gram + z ----
        const bf16x8 aw0 = *(const bf16x8*)&xs_rm[16*ws + la][8*g];
        const bf16x8 aw1 = *(const bf16x8*)&xs_rm[16*ws + la][32 + 8*g];
        f32x4 zt[4], Cg[4];
#pragma unroll
        for (int n = 0; n < 4; ++n) {
            bf16x8 b0 = *(const bf16x8*)&xs_rm[16*n + la][8*g];
            bf16x8 b1 = *(const bf16x8*)&xs_rm[16*n + la][32 + 8*g];
            f32x4 cc = {0.f,0.f,0.f,0.f};
            cc = __builtin_amdgcn_mfma_f32_16x16x32_bf16(aw0, b0, cc, 0,0,0);
            cc = __builtin_amdgcn_mfma_f32_16x16x32_bf16(aw1, b1, cc, 0,0,0);
            Cg[n] = cc;
            bf16x8 w0 = *(const bf16x8*)&Wtb[16*n + la][8*g];
            bf16x8 w1 = *(const bf16x8*)&Wtb[16*n + la][32 + 8*g];
            f32x4 zz = {0.f,0.f,0.f,0.f};
            zz = __builtin_amdgcn_mfma_f32_16x16x32_bf16(aw0, w0, zz, 0,0,0);
            zz = __builtin_amdgcn_mfma_f32_16x16x32_bf16(aw1, w1, zz, 0,0,0);
            zt[n] = zz;
        }
#pragma unroll
        for (int n = 0; n < 4; ++n) { // Gram write via symmetry (b64)
            short4v sg;
#pragma unroll
            for (int i = 0; i < 4; ++i) sg[i] = cvt_bf16(Cg[n][i]);
            *(short4v*)&Gr[16*n + la][r0] = sg;
        }

        // ---- epilogue (fp32) ----
        float gsv[4][4];
#pragma unroll
        for (int i = 0; i < 4; ++i) {
            float z0 = zt[0][i]+bcol[0], z1 = zt[1][i]+bcol[1];
            float z2 = zt[2][i]+bcol[2], z3 = zt[3][i]+bcol[3];
            float szz = red16(z0*z0 + z1*z1 + z2*z2 + z3*z3);
            float sz  = red16(z0 + z1 + z2 + z3);
            float thd = red16(xkg[i][0]*thv[0] + xkg[i][1]*thv[1] +
                              xkg[i][2]*thv[2] + xkg[i][3]*thv[3]);
            float mu  = sz * (1.0f/DC);
            float var = szz*(1.0f/DC) - mu*mu;
            float rstd = rsqrtf(var + EPSF);
            float lr  = 1.0f/(1.0f + expf(-(thd + tb)));
            float eta = tok[i]*lr*(1.0f/DC);
            float zz4[4] = {z0,z1,z2,z3};
            float xh[4], gxh[4], a1v = 0.f, a2v = 0.f;
#pragma unroll
            for (int n = 0; n < 4; ++n) {
                xh[n] = (zz4[n]-mu)*rstd;
                float y  = fmaf(gam[n], xh[n], bet[n]);
                float go = y - xvg[i][n] + xkg[i][n];
                gxh[n] = go*gam[n];
                a1v += gxh[n];
                a2v = fmaf(gxh[n], xh[n], a2v);
            }
            float s1 = red16(a1v), s2 = red16(a2v);
            float sc = rstd*(1.0f/DC)*eta;
#pragma unroll
            for (int n = 0; n < 4; ++n)
                gsv[i][n] = (64.f*gxh[n] - s1 - xh[n]*s2)*sc;
        }
#pragma unroll
        for (int n = 0; n < 4; ++n) { // gsT (b64)
            short4v sg;
#pragma unroll
            for (int i = 0; i < 4; ++i) sg[i] = cvt_bf16(gsv[i][n]);
            *(short4v*)&gsT[16*n + la][r0] = sg;
        }
        float dbl[4];
#pragma unroll
        for (int n = 0; n < 4; ++n) {
            float dd = gsv[0][n]+gsv[1][n]+gsv[2][n]+gsv[3][n];
            dd += __shfl_xor(dd, 16);
            dd += __shfl_xor(dd, 32);
            dbl[n] = dd;
        }
        if (l < 16) {
            f32x4 dv = {dbl[0], dbl[1], dbl[2], dbl[3]};
            *(f32x4*)&dbp[ws][4*la] = dv;
        }
        __syncthreads();   // sync2: gsT, Gr, dbp ready; xs_rm/Wtb reads done

        // ---- P2 ----
        float xkgN[4][4], xvgN[4][4];
        if (c + 1 < NCC) {
            const float* xkn = xkb + (c+1)*CSC*DC;
            const float* xvn = xvb + (c+1)*CSC*DC;
#pragma unroll
            for (int i = 0; i < 4; ++i)
#pragma unroll
                for (int n = 0; n < 4; ++n) {
                    xkgN[i][n] = xkn[(r0+i)*DC + 16*n + la];
                    xvgN[i][n] = xvn[(r0+i)*DC + 16*n + la];
                }
        }

        const bf16x8 ax0 = *(const bf16x8*)&xsT[cb][16*ws + la][8*g];
        const bf16x8 ax1 = *(const bf16x8*)&xsT[cb][16*ws + la][32 + 8*g];
        const bf16x8 ar0 = *(const bf16x8*)&Gr[16*ws + la][8*g];
        const bf16x8 ar1 = *(const bf16x8*)&Gr[16*ws + la][32 + 8*g];
        f32x4 outv[4];
#pragma unroll
        for (int n = 0; n < 4; ++n) {
            bf16x8 q0 = *(const bf16x8*)&gsT[16*n + la][8*g];
            bf16x8 q1 = *(const bf16x8*)&gsT[16*n + la][32 + 8*g];
            f32x4 dw = {0.f,0.f,0.f,0.f};
            dw = __builtin_amdgcn_mfma_f32_16x16x32_bf16(ax0, q0, dw, 0,0,0);
            dw = __builtin_amdgcn_mfma_f32_16x16x32_bf16(ax1, q1, dw, 0,0,0);
#pragma unroll
            for (int i = 0; i < 4; ++i) Wreg[i][n] -= dw[i];
            f32x4 og = {0.f,0.f,0.f,0.f};
            og = __builtin_amdgcn_mfma_f32_16x16x32_bf16(ar0, q0, og, 0,0,0);
            og = __builtin_amdgcn_mfma_f32_16x16x32_bf16(ar1, q1, og, 0,0,0);
            outv[n] = og;
        }
#pragma unroll
        for (int n = 0; n < 4; ++n) { // updated W -> Wtb (b64)
            short4v sw;
#pragma unroll
            for (int i = 0; i < 4; ++i) sw[i] = cvt_bf16(Wreg[i][n]);
            *(short4v*)&Wtb[16*n + la][r0] = sw;
        }
        {   // bias update (fixed-order, identical across waves of this seq)
            f32x4 d0v = *(const f32x4*)&dbp[0][4*la];
            f32x4 d1v = *(const f32x4*)&dbp[1][4*la];
            f32x4 d2v = *(const f32x4*)&dbp[2][4*la];
            f32x4 d3v = *(const f32x4*)&dbp[3][4*la];
#pragma unroll
            for (int n = 0; n < 4; ++n)
                bcol[n] -= d0v[n] + d1v[n] + d2v[n] + d3v[n];
        }
        // out = zt - Gram@gs + b_new
        float* oc = ob + c*CSC*DC;
#pragma unroll
        for (int i = 0; i < 4; ++i)
#pragma unroll
            for (int n = 0; n < 4; ++n)
                oc[(r0+i)*DC + 16*n + la] = zt[n][i] - outv[n][i] + bcol[n];

        // stage chunk c+1: xs_rm from xl, xsT[cb^1] from xkgN regs
        if (c + 1 < NCC) {
#pragma unroll
            for (int i4 = 0; i4 < 4; ++i4) {
                int f = ts + 256*i4, k = f >> 4, j = f & 15;
                short4v s4;
                s4[0]=cvt_bf16(xl[i4].x); s4[1]=cvt_bf16(xl[i4].y);
                s4[2]=cvt_bf16(xl[i4].z); s4[3]=cvt_bf16(xl[i4].w);
                *(short4v*)&xs_rm[k][4*j] = s4;
            }
#pragma unroll
            for (int n = 0; n < 4; ++n) {
                short4v sv;
#pragma unroll
                for (int i = 0; i < 4; ++i) sv[i] = cvt_bf16(xkgN[i][n]);
                *(short4v*)&xsT[cb ^ 1][16*n + la][r0] = sv;
            }
#pragma unroll
            for (int i = 0; i < 4; ++i)
#pragma unroll
                for (int n = 0; n < 4; ++n) {
                    xkg[i][n] = xkgN[i][n];
                    xvg[i][n] = xvgN[i][n];
                }
        }
        __syncthreads();   // sync3: Wtb + staged next-chunk data ready
    }
}

extern "C" void kernel_launch(void* const* d_in, const int* in_sizes, int n_in,
                              void* d_out, int out_size, void* d_ws, size_t ws_size,
                              hipStream_t stream) {
    const float* xk         = (const float*)d_in[0];
    const float* xv         = (const float*)d_in[1];
    const float* weight     = (const float*)d_in[2];
    const float* bias       = (const float*)d_in[3];
    const float* gamma      = (const float*)d_in[4];
    const float* beta       = (const float*)d_in[5];
    const float* theta      = (const float*)d_in[6];
    const float* theta_bias = (const float*)d_in[7];
    const float* alpha      = (const float*)d_in[8];
    float* out = (float*)d_out;

    (void)hipFuncSetAttribute((const void*)ttt_kernel,
                              hipFuncAttributeMaxDynamicSharedMemorySize,
                              2 * SEQB);
    ttt_kernel<<<NB * NH / 2, 512, 2 * SEQB, stream>>>(xk, xv, weight, bias,
                                                       gamma, beta, theta,
                                                       theta_bias, alpha, out);
}

// Round 6
// 206.827 us; speedup vs baseline: 1.5742x; 1.5742x over previous
//
#include <hip/hip_runtime.h>
#include <hip/hip_bf16.h>
#include <math.h>

#define NCC 64
#define CSC 64
#define DC 64
#define S 72            // bf16 LDS row stride (144 B rows)
#define SZ 68           // zT fp32 row stride
#define EPSF 1e-6f
#define LDS_BYTES 82944

typedef __attribute__((ext_vector_type(8))) short bf16x8;   // MFMA A/B frag
typedef __attribute__((ext_vector_type(4))) float f32x4;    // MFMA C/D frag
typedef __attribute__((ext_vector_type(4))) short short4v;

static __device__ __forceinline__ short cvt_bf16(float x) { // HW RNE via compiler
    union { __hip_bfloat16 b; short s; } u;
    u.b = __float2bfloat16(x);
    return u.s;
}
static __device__ __forceinline__ float red16(float v) {    // sum over 16-lane group
    v += __shfl_xor(v, 1); v += __shfl_xor(v, 2);
    v += __shfl_xor(v, 4); v += __shfl_xor(v, 8);
    return v;
}

__global__ __launch_bounds__(512, 1) void ttt_kernel(
    const float* __restrict__ xk, const float* __restrict__ xv,
    const float* __restrict__ weight, const float* __restrict__ bias,
    const float* __restrict__ gamma, const float* __restrict__ beta,
    const float* __restrict__ theta, const float* __restrict__ theta_bias,
    const float* __restrict__ alpha, float* __restrict__ out)
{
    extern __shared__ char sb[];
    auto xs_rm = (short (*)[CSC][S])(sb);             // [2][64][S] xk row-major
    auto xsT   = (short (*)[DC][S]) (sb + 18432);     // [2][64][S] xk^T (A of dW)
    auto gsT   = (short (*)[S])     (sb + 36864);     // gs^T (B of dW and out)
    auto Gr    = (short (*)[S])     (sb + 46080);     // Gram (A of out)
    auto Wtb   = (short (*)[S])     (sb + 55296);     // W [e][d] (B of z)
    auto zT    = (float (*)[SZ])    (sb + 64512);     // z pre-bias, [e][k] fp32
    auto dbp   = (float (*)[DC])    (sb + 81920);     // db partials

    const int t  = threadIdx.x;
    const int w  = t >> 6;            // wave 0..7
    const bool lo = (w < 4);          // state half vs output half
    const int ws = w & 3;             // band within half
    const int l  = t & 63;
    const int g  = l >> 4, la = l & 15;
    const int r0 = 16*ws + 4*g;       // first owned row / d-row
    const int ts = 64*ws + l;         // per-half thread id 0..255
    const int bh = blockIdx.x;        // 0..63
    const int h  = bh & 15;

    const size_t bh_off = (size_t)bh * NCC*CSC*DC;
    const float* xkb = xk + bh_off;
    const float* xvb = xv + bh_off;
    float*       ob  = out + bh_off;

    float bcol[4];                    // bias state replica (both halves)
#pragma unroll
    for (int n = 0; n < 4; ++n) bcol[n] = bias[h*DC + 16*n + la];

    float gam[4], bet[4], thv[4], tok[4], tb = 0.f;
    float Wreg[4][4];                 // low half: W state
    float xkg[4][4], xvg[4][4];       // low half: epilogue rows
    float4 xl[4];                     // high half: rm staging
    float xkh[4][4];                  // high half: xsT staging rows

    if (lo) {
#pragma unroll
        for (int n = 0; n < 4; ++n) {
            gam[n] = gamma[h*DC + 16*n + la];
            bet[n] = beta [h*DC + 16*n + la];
            thv[n] = theta[h*DC + 16*n + la];
        }
        tb = theta_bias[h];
#pragma unroll
        for (int i = 0; i < 4; ++i)
            tok[i] = fmaxf(1.0f/(float)(r0+i+1) + alpha[r0+i], 0.0f);
        const float* wg = weight + h*DC*DC;
#pragma unroll
        for (int i = 0; i < 4; ++i)
#pragma unroll
            for (int n = 0; n < 4; ++n)
                Wreg[i][n] = wg[(r0+i)*DC + 16*n + la];
#pragma unroll
        for (int n = 0; n < 4; ++n) {
            short4v sv;
#pragma unroll
            for (int i = 0; i < 4; ++i) sv[i] = cvt_bf16(Wreg[i][n]);
            *(short4v*)&Wtb[16*n + la][r0] = sv;
        }
#pragma unroll
        for (int i = 0; i < 4; ++i)
#pragma unroll
            for (int n = 0; n < 4; ++n) {
                xkg[i][n] = xkb[(r0+i)*DC + 16*n + la];
                xvg[i][n] = xvb[(r0+i)*DC + 16*n + la];
            }
    } else {
#pragma unroll
        for (int i4 = 0; i4 < 4; ++i4) xl[i4] = ((const float4*)xkb)[ts + 256*i4];
#pragma unroll
        for (int i = 0; i < 4; ++i)
#pragma unroll
            for (int n = 0; n < 4; ++n)
                xkh[i][n] = xkb[(r0+i)*DC + 16*n + la];
#pragma unroll
        for (int i4 = 0; i4 < 4; ++i4) {    // stage chunk 0
            int f = ts + 256*i4, k = f >> 4, j = f & 15;
            short4v s4;
            s4[0]=cvt_bf16(xl[i4].x); s4[1]=cvt_bf16(xl[i4].y);
            s4[2]=cvt_bf16(xl[i4].z); s4[3]=cvt_bf16(xl[i4].w);
            *(short4v*)&xs_rm[0][k][4*j] = s4;
        }
#pragma unroll
        for (int n = 0; n < 4; ++n) {
            short4v sv;
#pragma unroll
            for (int i = 0; i < 4; ++i) sv[i] = cvt_bf16(xkh[i][n]);
            *(short4v*)&xsT[0][16*n + la][r0] = sv;
        }
    }
    __syncthreads();

    for (int c = 0; c < NCC; ++c) {
        const int cb = c & 1, nb = cb ^ 1;

        if (lo) {
            // ---- P1-low: z = xs@W, then epilogue -> gsT/dbp ----
            const bf16x8 a0 = *(const bf16x8*)&xs_rm[cb][16*ws + la][8*g];
            const bf16x8 a1 = *(const bf16x8*)&xs_rm[cb][16*ws + la][32 + 8*g];
            f32x4 zt[4];
#pragma unroll
            for (int n = 0; n < 4; ++n) {
                bf16x8 w0 = *(const bf16x8*)&Wtb[16*n + la][8*g];
                bf16x8 w1 = *(const bf16x8*)&Wtb[16*n + la][32 + 8*g];
                f32x4 zz = {0.f,0.f,0.f,0.f};
                zz = __builtin_amdgcn_mfma_f32_16x16x32_bf16(a0, w0, zz, 0,0,0);
                zz = __builtin_amdgcn_mfma_f32_16x16x32_bf16(a1, w1, zz, 0,0,0);
                zt[n] = zz;
                *(f32x4*)&zT[16*n + la][r0] = zz;   // pre-bias z for out half
            }
            float gsv[4][4];
#pragma unroll
            for (int i = 0; i < 4; ++i) {
                float z0 = zt[0][i]+bcol[0], z1 = zt[1][i]+bcol[1];
                float z2 = zt[2][i]+bcol[2], z3 = zt[3][i]+bcol[3];
                float szz = red16(z0*z0 + z1*z1 + z2*z2 + z3*z3);
                float sz  = red16(z0 + z1 + z2 + z3);
                float thd = red16(xkg[i][0]*thv[0] + xkg[i][1]*thv[1] +
                                  xkg[i][2]*thv[2] + xkg[i][3]*thv[3]);
                float mu  = sz * (1.0f/DC);
                float var = szz*(1.0f/DC) - mu*mu;
                float rstd = rsqrtf(var + EPSF);
                float lr  = 1.0f/(1.0f + expf(-(thd + tb)));
                float eta = tok[i]*lr*(1.0f/DC);
                float zz4[4] = {z0,z1,z2,z3};
                float xh[4], gxh[4], a1v = 0.f, a2v = 0.f;
#pragma unroll
                for (int n = 0; n < 4; ++n) {
                    xh[n] = (zz4[n]-mu)*rstd;
                    float y  = fmaf(gam[n], xh[n], bet[n]);
                    float go = y - xvg[i][n] + xkg[i][n];
                    gxh[n] = go*gam[n];
                    a1v += gxh[n];
                    a2v = fmaf(gxh[n], xh[n], a2v);
                }
                float s1 = red16(a1v), s2 = red16(a2v);
                float sc = rstd*(1.0f/DC)*eta;
#pragma unroll
                for (int n = 0; n < 4; ++n)
                    gsv[i][n] = (64.f*gxh[n] - s1 - xh[n]*s2)*sc;
            }
#pragma unroll
            for (int n = 0; n < 4; ++n) {
                short4v sg;
#pragma unroll
                for (int i = 0; i < 4; ++i) sg[i] = cvt_bf16(gsv[i][n]);
                *(short4v*)&gsT[16*n + la][r0] = sg;
            }
            float dbl[4];
#pragma unroll
            for (int n = 0; n < 4; ++n) {
                float dd = gsv[0][n]+gsv[1][n]+gsv[2][n]+gsv[3][n];
                dd += __shfl_xor(dd, 16);
                dd += __shfl_xor(dd, 32);
                dbl[n] = dd;
            }
            if (l < 16) {
                f32x4 dv = {dbl[0], dbl[1], dbl[2], dbl[3]};
                *(f32x4*)&dbp[ws][4*la] = dv;
            }
        } else {
            // ---- P1-high: Gram + next-chunk staging (overlaps epilogue) ----
            const bf16x8 a0 = *(const bf16x8*)&xs_rm[cb][16*ws + la][8*g];
            const bf16x8 a1 = *(const bf16x8*)&xs_rm[cb][16*ws + la][32 + 8*g];
#pragma unroll
            for (int n = 0; n < 4; ++n) {
                bf16x8 b0 = *(const bf16x8*)&xs_rm[cb][16*n + la][8*g];
                bf16x8 b1 = *(const bf16x8*)&xs_rm[cb][16*n + la][32 + 8*g];
                f32x4 cc = {0.f,0.f,0.f,0.f};
                cc = __builtin_amdgcn_mfma_f32_16x16x32_bf16(a0, b0, cc, 0,0,0);
                cc = __builtin_amdgcn_mfma_f32_16x16x32_bf16(a1, b1, cc, 0,0,0);
                short4v sg;                         // Gram write via symmetry
#pragma unroll
                for (int i = 0; i < 4; ++i) sg[i] = cvt_bf16(cc[i]);
                *(short4v*)&Gr[16*n + la][r0] = sg;
            }
            if (c + 1 < NCC) {
                const float* xkn = xkb + (c+1)*CSC*DC;
#pragma unroll
                for (int i4 = 0; i4 < 4; ++i4) xl[i4] = ((const float4*)xkn)[ts + 256*i4];
#pragma unroll
                for (int i = 0; i < 4; ++i)
#pragma unroll
                    for (int n = 0; n < 4; ++n)
                        xkh[i][n] = xkn[(r0+i)*DC + 16*n + la];
#pragma unroll
                for (int i4 = 0; i4 < 4; ++i4) {
                    int f = ts + 256*i4, k = f >> 4, j = f & 15;
                    short4v s4;
                    s4[0]=cvt_bf16(xl[i4].x); s4[1]=cvt_bf16(xl[i4].y);
                    s4[2]=cvt_bf16(xl[i4].z); s4[3]=cvt_bf16(xl[i4].w);
                    *(short4v*)&xs_rm[nb][k][4*j] = s4;
                }
#pragma unroll
                for (int n = 0; n < 4; ++n) {
                    short4v sv;
#pragma unroll
                    for (int i = 0; i < 4; ++i) sv[i] = cvt_bf16(xkh[i][n]);
                    *(short4v*)&xsT[nb][16*n + la][r0] = sv;
                }
            }
        }
        __syncthreads();    // B: gsT, dbp, Gr, zT ready

        {   // bias state update — fixed order, replicated in both halves
            f32x4 d0v = *(const f32x4*)&dbp[0][4*la];
            f32x4 d1v = *(const f32x4*)&dbp[1][4*la];
            f32x4 d2v = *(const f32x4*)&dbp[2][4*la];
            f32x4 d3v = *(const f32x4*)&dbp[3][4*la];
#pragma unroll
            for (int n = 0; n < 4; ++n)
                bcol[n] -= d0v[n] + d1v[n] + d2v[n] + d3v[n];
        }

        if (lo) {
            // ---- P2-low: dW + W state update + Wtb re-encode ----
            const bf16x8 ax0 = *(const bf16x8*)&xsT[cb][16*ws + la][8*g];
            const bf16x8 ax1 = *(const bf16x8*)&xsT[cb][16*ws + la][32 + 8*g];
#pragma unroll
            for (int n = 0; n < 4; ++n) {
                bf16x8 q0 = *(const bf16x8*)&gsT[16*n + la][8*g];
                bf16x8 q1 = *(const bf16x8*)&gsT[16*n + la][32 + 8*g];
                f32x4 dw = {0.f,0.f,0.f,0.f};
                dw = __builtin_amdgcn_mfma_f32_16x16x32_bf16(ax0, q0, dw, 0,0,0);
                dw = __builtin_amdgcn_mfma_f32_16x16x32_bf16(ax1, q1, dw, 0,0,0);
                short4v sw;
#pragma unroll
                for (int i = 0; i < 4; ++i) {
                    Wreg[i][n] -= dw[i];
                    sw[i] = cvt_bf16(Wreg[i][n]);
                }
                *(short4v*)&Wtb[16*n + la][r0] = sw;
            }
            if (c + 1 < NCC) {      // prefetch next epilogue rows (L2-hot)
                const float* xkn = xkb + (c+1)*CSC*DC;
                const float* xvn = xvb + (c+1)*CSC*DC;
#pragma unroll
                for (int i = 0; i < 4; ++i)
#pragma unroll
                    for (int n = 0; n < 4; ++n) {
                        xkg[i][n] = xkn[(r0+i)*DC + 16*n + la];
                        xvg[i][n] = xvn[(r0+i)*DC + 16*n + la];
                    }
            }
        } else {
            // ---- P2-high: out = z - Gram@gs + b_new ----
            const bf16x8 ar0 = *(const bf16x8*)&Gr[16*ws + la][8*g];
            const bf16x8 ar1 = *(const bf16x8*)&Gr[16*ws + la][32 + 8*g];
            float* oc = ob + c*CSC*DC;
#pragma unroll
            for (int n = 0; n < 4; ++n) {
                bf16x8 q0 = *(const bf16x8*)&gsT[16*n + la][8*g];
                bf16x8 q1 = *(const bf16x8*)&gsT[16*n + la][32 + 8*g];
                f32x4 og = {0.f,0.f,0.f,0.f};
                og = __builtin_amdgcn_mfma_f32_16x16x32_bf16(ar0, q0, og, 0,0,0);
                og = __builtin_amdgcn_mfma_f32_16x16x32_bf16(ar1, q1, og, 0,0,0);
                f32x4 zv = *(const f32x4*)&zT[16*n + la][r0];
#pragma unroll
                for (int i = 0; i < 4; ++i)
                    oc[(r0+i)*DC + 16*n + la] = zv[i] - og[i] + bcol[n];
            }
        }
        __syncthreads();    // C: Wtb + staged next-chunk buffers ready
    }
}

extern "C" void kernel_launch(void* const* d_in, const int* in_sizes, int n_in,
                              void* d_out, int out_size, void* d_ws, size_t ws_size,
                              hipStream_t stream) {
    const float* xk         = (const float*)d_in[0];
    const float* xv         = (const float*)d_in[1];
    const float* weight     = (const float*)d_in[2];
    const float* bias       = (const float*)d_in[3];
    const float* gamma      = (const float*)d_in[4];
    const float* beta       = (const float*)d_in[5];
    const float* theta      = (const float*)d_in[6];
    const float* theta_bias = (const float*)d_in[7];
    const float* alpha      = (const float*)d_in[8];
    float* out = (float*)d_out;

    (void)hipFuncSetAttribute((const void*)ttt_kernel,
                              hipFuncAttributeMaxDynamicSharedMemorySize,
                              LDS_BYTES);
    ttt_kernel<<<64, 512, LDS_BYTES, stream>>>(xk, xv, weight, bias, gamma, beta,
                                               theta, theta_bias, alpha, out);
}

// Round 7
// 145.047 us; speedup vs baseline: 2.2446x; 1.4259x over previous
//
#include <hip/hip_runtime.h>
#include <hip/hip_bf16.h>
#include <math.h>

#define NCC 64
#define CSC 64
#define DC 64
#define S 72            // bf16 LDS row stride (144 B rows)
#define SZ 68           // zT fp32 row stride
#define EPSF 1e-6f
#define LDS_BYTES 82944

typedef __attribute__((ext_vector_type(8))) short bf16x8;   // MFMA A/B frag
typedef __attribute__((ext_vector_type(4))) float f32x4;    // MFMA C/D frag
typedef __attribute__((ext_vector_type(4))) short short4v;

static __device__ __forceinline__ short cvt_bf16(float x) { // HW RNE via compiler
    union { __hip_bfloat16 b; short s; } u;
    u.b = __float2bfloat16(x);
    return u.s;
}

// 16-lane sum via DPP row rotations: VALU-only, no DS-pipe traffic.
// row_ror:N = dpp_ctrl 0x120+N; DPP "row" = 16 lanes; rotations compose to
// a broadcast total after steps 1,2,4,8.
#define DPP_ROR_ADD(v, N)                                                     \
    do {                                                                      \
        union { float f; int i; } _u, _r;                                     \
        _u.f = (v);                                                           \
        _r.i = __builtin_amdgcn_mov_dpp(_u.i, 0x120 + (N), 0xF, 0xF, true);   \
        (v) += _r.f;                                                          \
    } while (0)

static __device__ __forceinline__ float red16(float v) {
    DPP_ROR_ADD(v, 1);
    DPP_ROR_ADD(v, 2);
    DPP_ROR_ADD(v, 4);
    DPP_ROR_ADD(v, 8);
    return v;
}

__global__ __launch_bounds__(512, 1) void ttt_kernel(
    const float* __restrict__ xk, const float* __restrict__ xv,
    const float* __restrict__ weight, const float* __restrict__ bias,
    const float* __restrict__ gamma, const float* __restrict__ beta,
    const float* __restrict__ theta, const float* __restrict__ theta_bias,
    const float* __restrict__ alpha, float* __restrict__ out)
{
    extern __shared__ char sb[];
    auto xs_rm = (short (*)[CSC][S])(sb);             // [2][64][S] xk row-major
    auto xsT   = (short (*)[DC][S]) (sb + 18432);     // [2][64][S] xk^T (A of dW)
    auto gsT   = (short (*)[S])     (sb + 36864);     // gs^T (B of dW and out)
    auto Gr    = (short (*)[S])     (sb + 46080);     // Gram (A of out)
    auto Wtb   = (short (*)[S])     (sb + 55296);     // W [e][d] (B of z)
    auto zT    = (float (*)[SZ])    (sb + 64512);     // z pre-bias, [e][k] fp32
    auto dbp   = (float (*)[DC])    (sb + 81920);     // db partials

    const int t  = threadIdx.x;
    const int w  = t >> 6;            // wave 0..7
    const bool lo = (w < 4);          // state half vs output half
    const int ws = w & 3;             // band within half
    const int l  = t & 63;
    const int g  = l >> 4, la = l & 15;
    const int r0 = 16*ws + 4*g;       // first owned row / d-row
    const int ts = 64*ws + l;         // per-half thread id 0..255
    const int bh = blockIdx.x;        // 0..63
    const int h  = bh & 15;

    const size_t bh_off = (size_t)bh * NCC*CSC*DC;
    const float* xkb = xk + bh_off;
    const float* xvb = xv + bh_off;
    float*       ob  = out + bh_off;

    float bcol[4];                    // bias state replica (both halves)
#pragma unroll
    for (int n = 0; n < 4; ++n) bcol[n] = bias[h*DC + 16*n + la];

    float gam[4], bet[4], thv[4], tok[4], tb = 0.f;
    float Wreg[4][4];                 // low half: W state
    float xkg[4][4], xvg[4][4];       // low half: epilogue rows
    float4 xl[4];                     // high half: rm staging
    float xkh[4][4];                  // high half: xsT staging rows

    if (lo) {
#pragma unroll
        for (int n = 0; n < 4; ++n) {
            gam[n] = gamma[h*DC + 16*n + la];
            bet[n] = beta [h*DC + 16*n + la];
            thv[n] = theta[h*DC + 16*n + la];
        }
        tb = theta_bias[h];
#pragma unroll
        for (int i = 0; i < 4; ++i)
            tok[i] = fmaxf(1.0f/(float)(r0+i+1) + alpha[r0+i], 0.0f);
        const float* wg = weight + h*DC*DC;
#pragma unroll
        for (int i = 0; i < 4; ++i)
#pragma unroll
            for (int n = 0; n < 4; ++n)
                Wreg[i][n] = wg[(r0+i)*DC + 16*n + la];
#pragma unroll
        for (int n = 0; n < 4; ++n) {
            short4v sv;
#pragma unroll
            for (int i = 0; i < 4; ++i) sv[i] = cvt_bf16(Wreg[i][n]);
            *(short4v*)&Wtb[16*n + la][r0] = sv;
        }
#pragma unroll
        for (int i = 0; i < 4; ++i)
#pragma unroll
            for (int n = 0; n < 4; ++n) {
                xkg[i][n] = xkb[(r0+i)*DC + 16*n + la];
                xvg[i][n] = xvb[(r0+i)*DC + 16*n + la];
            }
    } else {
#pragma unroll
        for (int i4 = 0; i4 < 4; ++i4) xl[i4] = ((const float4*)xkb)[ts + 256*i4];
#pragma unroll
        for (int i = 0; i < 4; ++i)
#pragma unroll
            for (int n = 0; n < 4; ++n)
                xkh[i][n] = xkb[(r0+i)*DC + 16*n + la];
#pragma unroll
        for (int i4 = 0; i4 < 4; ++i4) {    // stage chunk 0
            int f = ts + 256*i4, k = f >> 4, j = f & 15;
            short4v s4;
            s4[0]=cvt_bf16(xl[i4].x); s4[1]=cvt_bf16(xl[i4].y);
            s4[2]=cvt_bf16(xl[i4].z); s4[3]=cvt_bf16(xl[i4].w);
            *(short4v*)&xs_rm[0][k][4*j] = s4;
        }
#pragma unroll
        for (int n = 0; n < 4; ++n) {
            short4v sv;
#pragma unroll
            for (int i = 0; i < 4; ++i) sv[i] = cvt_bf16(xkh[i][n]);
            *(short4v*)&xsT[0][16*n + la][r0] = sv;
        }
    }
    __syncthreads();

    for (int c = 0; c < NCC; ++c) {
        const int cb = c & 1, nb = cb ^ 1;

        if (lo) {
            // ---- P1-low: z = xs@W, then epilogue -> gsT/dbp ----
            const bf16x8 a0 = *(const bf16x8*)&xs_rm[cb][16*ws + la][8*g];
            const bf16x8 a1 = *(const bf16x8*)&xs_rm[cb][16*ws + la][32 + 8*g];
            f32x4 zt[4];
#pragma unroll
            for (int n = 0; n < 4; ++n) {
                bf16x8 w0 = *(const bf16x8*)&Wtb[16*n + la][8*g];
                bf16x8 w1 = *(const bf16x8*)&Wtb[16*n + la][32 + 8*g];
                f32x4 zz = {0.f,0.f,0.f,0.f};
                zz = __builtin_amdgcn_mfma_f32_16x16x32_bf16(a0, w0, zz, 0,0,0);
                zz = __builtin_amdgcn_mfma_f32_16x16x32_bf16(a1, w1, zz, 0,0,0);
                zt[n] = zz;
                *(f32x4*)&zT[16*n + la][r0] = zz;   // pre-bias z for out half
            }
            float gsv[4][4];
#pragma unroll
            for (int i = 0; i < 4; ++i) {
                float z0 = zt[0][i]+bcol[0], z1 = zt[1][i]+bcol[1];
                float z2 = zt[2][i]+bcol[2], z3 = zt[3][i]+bcol[3];
                float szz = red16(z0*z0 + z1*z1 + z2*z2 + z3*z3);
                float sz  = red16(z0 + z1 + z2 + z3);
                float thd = red16(xkg[i][0]*thv[0] + xkg[i][1]*thv[1] +
                                  xkg[i][2]*thv[2] + xkg[i][3]*thv[3]);
                float mu  = sz * (1.0f/DC);
                float var = szz*(1.0f/DC) - mu*mu;
                float rstd = rsqrtf(var + EPSF);
                float ex  = __expf(-(thd + tb));
                float lr  = __builtin_amdgcn_rcpf(1.0f + ex);
                float eta = tok[i]*lr*(1.0f/DC);
                float zz4[4] = {z0,z1,z2,z3};
                float xh[4], gxh[4], a1v = 0.f, a2v = 0.f;
#pragma unroll
                for (int n = 0; n < 4; ++n) {
                    xh[n] = (zz4[n]-mu)*rstd;
                    float y  = fmaf(gam[n], xh[n], bet[n]);
                    float go = y - xvg[i][n] + xkg[i][n];
                    gxh[n] = go*gam[n];
                    a1v += gxh[n];
                    a2v = fmaf(gxh[n], xh[n], a2v);
                }
                float s1 = red16(a1v), s2 = red16(a2v);
                float sc = rstd*(1.0f/DC)*eta;
#pragma unroll
                for (int n = 0; n < 4; ++n)
                    gsv[i][n] = (64.f*gxh[n] - s1 - xh[n]*s2)*sc;
            }
#pragma unroll
            for (int n = 0; n < 4; ++n) {
                short4v sg;
#pragma unroll
                for (int i = 0; i < 4; ++i) sg[i] = cvt_bf16(gsv[i][n]);
                *(short4v*)&gsT[16*n + la][r0] = sg;
            }
            float dbl[4];
#pragma unroll
            for (int n = 0; n < 4; ++n) {
                float dd = gsv[0][n]+gsv[1][n]+gsv[2][n]+gsv[3][n];
                dd += __shfl_xor(dd, 16);
                dd += __shfl_xor(dd, 32);
                dbl[n] = dd;
            }
            if (l < 16) {
                f32x4 dv = {dbl[0], dbl[1], dbl[2], dbl[3]};
                *(f32x4*)&dbp[ws][4*la] = dv;
            }
        } else {
            // ---- P1-high: Gram + next-chunk staging (overlaps epilogue) ----
            const bf16x8 a0 = *(const bf16x8*)&xs_rm[cb][16*ws + la][8*g];
            const bf16x8 a1 = *(const bf16x8*)&xs_rm[cb][16*ws + la][32 + 8*g];
#pragma unroll
            for (int n = 0; n < 4; ++n) {
                bf16x8 b0 = *(const bf16x8*)&xs_rm[cb][16*n + la][8*g];
                bf16x8 b1 = *(const bf16x8*)&xs_rm[cb][16*n + la][32 + 8*g];
                f32x4 cc = {0.f,0.f,0.f,0.f};
                cc = __builtin_amdgcn_mfma_f32_16x16x32_bf16(a0, b0, cc, 0,0,0);
                cc = __builtin_amdgcn_mfma_f32_16x16x32_bf16(a1, b1, cc, 0,0,0);
                short4v sg;                         // Gram write via symmetry
#pragma unroll
                for (int i = 0; i < 4; ++i) sg[i] = cvt_bf16(cc[i]);
                *(short4v*)&Gr[16*n + la][r0] = sg;
            }
            if (c + 1 < NCC) {
                const float* xkn = xkb + (c+1)*CSC*DC;
#pragma unroll
                for (int i4 = 0; i4 < 4; ++i4) xl[i4] = ((const float4*)xkn)[ts + 256*i4];
#pragma unroll
                for (int i = 0; i < 4; ++i)
#pragma unroll
                    for (int n = 0; n < 4; ++n)
                        xkh[i][n] = xkn[(r0+i)*DC + 16*n + la];
#pragma unroll
                for (int i4 = 0; i4 < 4; ++i4) {
                    int f = ts + 256*i4, k = f >> 4, j = f & 15;
                    short4v s4;
                    s4[0]=cvt_bf16(xl[i4].x); s4[1]=cvt_bf16(xl[i4].y);
                    s4[2]=cvt_bf16(xl[i4].z); s4[3]=cvt_bf16(xl[i4].w);
                    *(short4v*)&xs_rm[nb][k][4*j] = s4;
                }
#pragma unroll
                for (int n = 0; n < 4; ++n) {
                    short4v sv;
#pragma unroll
                    for (int i = 0; i < 4; ++i) sv[i] = cvt_bf16(xkh[i][n]);
                    *(short4v*)&xsT[nb][16*n + la][r0] = sv;
                }
            }
        }
        __syncthreads();    // B: gsT, dbp, Gr, zT ready

        {   // bias state update — fixed order, replicated in both halves
            f32x4 d0v = *(const f32x4*)&dbp[0][4*la];
            f32x4 d1v = *(const f32x4*)&dbp[1][4*la];
            f32x4 d2v = *(const f32x4*)&dbp[2][4*la];
            f32x4 d3v = *(const f32x4*)&dbp[3][4*la];
#pragma unroll
            for (int n = 0; n < 4; ++n)
                bcol[n] -= d0v[n] + d1v[n] + d2v[n] + d3v[n];
        }

        if (lo) {
            // ---- P2-low: dW + W state update + Wtb re-encode ----
            const bf16x8 ax0 = *(const bf16x8*)&xsT[cb][16*ws + la][8*g];
            const bf16x8 ax1 = *(const bf16x8*)&xsT[cb][16*ws + la][32 + 8*g];
#pragma unroll
            for (int n = 0; n < 4; ++n) {
                bf16x8 q0 = *(const bf16x8*)&gsT[16*n + la][8*g];
                bf16x8 q1 = *(const bf16x8*)&gsT[16*n + la][32 + 8*g];
                f32x4 dw = {0.f,0.f,0.f,0.f};
                dw = __builtin_amdgcn_mfma_f32_16x16x32_bf16(ax0, q0, dw, 0,0,0);
                dw = __builtin_amdgcn_mfma_f32_16x16x32_bf16(ax1, q1, dw, 0,0,0);
                short4v sw;
#pragma unroll
                for (int i = 0; i < 4; ++i) {
                    Wreg[i][n] -= dw[i];
                    sw[i] = cvt_bf16(Wreg[i][n]);
                }
                *(short4v*)&Wtb[16*n + la][r0] = sw;
            }
            if (c + 1 < NCC) {      // prefetch next epilogue rows (L2-hot)
                const float* xkn = xkb + (c+1)*CSC*DC;
                const float* xvn = xvb + (c+1)*CSC*DC;
#pragma unroll
                for (int i = 0; i < 4; ++i)
#pragma unroll
                    for (int n = 0; n < 4; ++n) {
                        xkg[i][n] = xkn[(r0+i)*DC + 16*n + la];
                        xvg[i][n] = xvn[(r0+i)*DC + 16*n + la];
                    }
            }
        } else {
            // ---- P2-high: out = z - Gram@gs + b_new ----
            const bf16x8 ar0 = *(const bf16x8*)&Gr[16*ws + la][8*g];
            const bf16x8 ar1 = *(const bf16x8*)&Gr[16*ws + la][32 + 8*g];
            float* oc = ob + c*CSC*DC;
#pragma unroll
            for (int n = 0; n < 4; ++n) {
                bf16x8 q0 = *(const bf16x8*)&gsT[16*n + la][8*g];
                bf16x8 q1 = *(const bf16x8*)&gsT[16*n + la][32 + 8*g];
                f32x4 og = {0.f,0.f,0.f,0.f};
                og = __builtin_amdgcn_mfma_f32_16x16x32_bf16(ar0, q0, og, 0,0,0);
                og = __builtin_amdgcn_mfma_f32_16x16x32_bf16(ar1, q1, og, 0,0,0);
                f32x4 zv = *(const f32x4*)&zT[16*n + la][r0];
#pragma unroll
                for (int i = 0; i < 4; ++i)
                    oc[(r0+i)*DC + 16*n + la] = zv[i] - og[i] + bcol[n];
            }
        }
        __syncthreads();    // C: Wtb + staged next-chunk buffers ready
    }
}

extern "C" void kernel_launch(void* const* d_in, const int* in_sizes, int n_in,
                              void* d_out, int out_size, void* d_ws, size_t ws_size,
                              hipStream_t stream) {
    const float* xk         = (const float*)d_in[0];
    const float* xv         = (const float*)d_in[1];
    const float* weight     = (const float*)d_in[2];
    const float* bias       = (const float*)d_in[3];
    const float* gamma      = (const float*)d_in[4];
    const float* beta       = (const float*)d_in[5];
    const float* theta      = (const float*)d_in[6];
    const float* theta_bias = (const float*)d_in[7];
    const float* alpha      = (const float*)d_in[8];
    float* out = (float*)d_out;

    (void)hipFuncSetAttribute((const void*)ttt_kernel,
                              hipFuncAttributeMaxDynamicSharedMemorySize,
                              LDS_BYTES);
    ttt_kernel<<<64, 512, LDS_BYTES, stream>>>(xk, xv, weight, bias, gamma, beta,
                                               theta, theta_bias, alpha, out);
}